// Round 11
// baseline (450.743 us; speedup 1.0000x reference)
//
#include <hip/hip_runtime.h>
#include <hip/hip_bf16.h>

#define C_EMB 384
#define T_SEQ 256
#define B_BATCH 128
#define M_ROWS (B_BATCH * T_SEQ)   // 32768
#define QKV_LD 1152                // row stride of qkv buffer (bf16)
#define BK 64                      // K-tile = two 32-elem panels (each 64-B rows, m97 layout)

typedef __bf16 bf16_8 __attribute__((ext_vector_type(8)));
typedef float f32x4 __attribute__((ext_vector_type(4)));

// Async global->LDS 16-B copy. Dest is wave-uniform base + lane*16 (m104/m108).
__device__ __forceinline__ void load16_lds(const __bf16* g, __bf16* l) {
    __builtin_amdgcn_global_load_lds(
        (const __attribute__((address_space(1))) unsigned int*)g,
        (__attribute__((address_space(3))) unsigned int*)l, 16, 0, 0);
}

// ---------------- All-weights cast + transpose (single dispatch) ----------------------
// Wt[n][k] = bf16(W[k][n]) for the 4 weight matrices; block ranges select the matrix.
__global__ __launch_bounds__(256) void cast_all_kernel(const float* __restrict__ Wa,
                                                       const float* __restrict__ Wp,
                                                       const float* __restrict__ W1,
                                                       const float* __restrict__ W2,
                                                       __bf16* __restrict__ Wa_t,
                                                       __bf16* __restrict__ Wp_t,
                                                       __bf16* __restrict__ W1_t,
                                                       __bf16* __restrict__ W2_t) {
    int bid = blockIdx.x;
    const float* W; __bf16* Wt; int K, N, tx_n;
    // tile counts: Wa 36x12=432, Wp 12x12=144, W1 48x12=576, W2 12x48=576
    if (bid < 432)      { W = Wa; Wt = Wa_t; K = 384;  N = 1152; tx_n = 36; }
    else if (bid < 576) { bid -= 432; W = Wp; Wt = Wp_t; K = 384;  N = 384;  tx_n = 12; }
    else if (bid < 1152){ bid -= 576; W = W1; Wt = W1_t; K = 384;  N = 1536; tx_n = 48; }
    else                { bid -= 1152; W = W2; Wt = W2_t; K = 1536; N = 384;  tx_n = 12; }
    int n0 = (bid % tx_n) * 32, k0 = (bid / tx_n) * 32;

    __shared__ float t[32][33];
    int tx = threadIdx.x & 31, ty = threadIdx.x >> 5;
#pragma unroll
    for (int i = 0; i < 4; ++i)
        t[ty + i * 8][tx] = W[(size_t)(k0 + ty + i * 8) * N + n0 + tx];
    __syncthreads();
#pragma unroll
    for (int i = 0; i < 4; ++i) {
        int n = ty + i * 8;
        Wt[(size_t)(n0 + n) * K + k0 + tx] = (__bf16)t[tx][n];
    }
}

// ---------------- LayerNorm: one block (384 threads) per row, bf16 out ----------------
__global__ __launch_bounds__(384) void ln_kernel(const float* __restrict__ x,
                                                 const float* __restrict__ g,
                                                 const float* __restrict__ bta,
                                                 __bf16* __restrict__ out) {
    int row = blockIdx.x;
    int c = threadIdx.x;
    float v = x[(size_t)row * C_EMB + c];

    __shared__ float red[6];
    float s = v;
#pragma unroll
    for (int o = 32; o; o >>= 1) s += __shfl_down(s, o);
    if ((c & 63) == 0) red[c >> 6] = s;
    __syncthreads();
    float mu = (red[0] + red[1] + red[2] + red[3] + red[4] + red[5]) * (1.0f / C_EMB);

    float d = v - mu;
    float s2 = d * d;
#pragma unroll
    for (int o = 32; o; o >>= 1) s2 += __shfl_down(s2, o);
    __syncthreads();
    if ((c & 63) == 0) red[c >> 6] = s2;
    __syncthreads();
    float var = (red[0] + red[1] + red[2] + red[3] + red[4] + red[5]) * (1.0f / C_EMB);

    out[(size_t)row * C_EMB + c] = (__bf16)(d * rsqrtf(var + 1e-5f) * g[c] + bta[c]);
}

// ---------------- Pipelined GEMM (r6 structure, TN=384): out = A @ Bt^T + bias -------
// TM=128 x TN=384, 512 thr, 4x2 wave grid, BK=64, dbuf 128 KB, 1 block/CU. Proven r6
// sync + swizzle. Used for qkv (K=384, N=1152).
template <int K, int NFULL, bool RELU, bool ACCUM>
__global__ __launch_bounds__(512, 1) void gemm_pipe(const __bf16* __restrict__ A,
                                                    const __bf16* __restrict__ Bt,   // [NFULL,K]
                                                    const float* __restrict__ bias,
                                                    void* __restrict__ out_) {
    __shared__ __align__(16) __bf16 At[2][128 * 64];   // 32 KB
    __shared__ __align__(16) __bf16 Bs[2][384 * 64];   // 96 KB

    int tid = threadIdx.x;
    int wave = tid >> 6, lane = tid & 63;
    int wr = wave >> 1, wc = wave & 1;          // 4x2 wave grid (r6-proven; 2x4 was -19%)
    int quad = lane >> 4, l16 = lane & 15;
    int bm = blockIdx.y * 128;
    int n0 = blockIdx.x * 384;
    int srow = lane >> 3;                       // row within 8-row group
    int sunit = (lane & 7) ^ srow;              // pre-swizzled source 16-B unit

    const __bf16* asrc0 = A + (size_t)(bm + srow) * K + sunit * 8;
    const __bf16* bsrc0 = Bt + (size_t)(n0 + srow) * K + sunit * 8;

    auto stage = [&](int buf, int k0) {
#pragma unroll
        for (int t = 0; t < 2; ++t) {
            int g = t * 8 + wave;               // 8-row group 0..15 (128 A rows)
            load16_lds(asrc0 + (size_t)(g * 8) * K + k0, &At[buf][g * 8 * 64]);
        }
#pragma unroll
        for (int t = 0; t < 6; ++t) {
            int g = t * 8 + wave;               // 8-row group 0..47 (384 B rows)
            load16_lds(bsrc0 + (size_t)(g * 8) * K + k0, &Bs[buf][g * 8 * 64]);
        }
    };

    f32x4 acc[2][12] = {};

    stage(0, 0);
    asm volatile("s_waitcnt vmcnt(0)" ::: "memory");
    __builtin_amdgcn_sched_barrier(0);
    __builtin_amdgcn_s_barrier();

#pragma unroll 2
    for (int kt = 0; kt < K / BK; ++kt) {
        int cur = kt & 1;
        if (kt < K / BK - 1) stage(cur ^ 1, (kt + 1) * BK);   // issue next-tile loads FIRST

        bf16_8 af[2][2];
#pragma unroll
        for (int p = 0; p < 2; ++p)
#pragma unroll
            for (int i = 0; i < 2; ++i) {
                int row = wr * 32 + i * 16 + l16;
                int u = (p * 4 + quad) ^ (row & 7);   // k = p*32 + quad*8
                af[i][p] = *reinterpret_cast<const bf16_8*>(&At[cur][row * 64 + u * 8]);
            }
#pragma unroll
        for (int p = 0; p < 2; ++p)
#pragma unroll
            for (int j = 0; j < 12; ++j) {
                int row = wc * 192 + j * 16 + l16;
                int u = (p * 4 + quad) ^ (row & 7);
                bf16_8 bf = *reinterpret_cast<const bf16_8*>(&Bs[cur][row * 64 + u * 8]);
                acc[0][j] = __builtin_amdgcn_mfma_f32_16x16x32_bf16(af[0][p], bf, acc[0][j], 0, 0, 0);
                acc[1][j] = __builtin_amdgcn_mfma_f32_16x16x32_bf16(af[1][p], bf, acc[1][j], 0, 0, 0);
            }

        asm volatile("s_waitcnt vmcnt(0)" ::: "memory");
        __builtin_amdgcn_sched_barrier(0);
        __builtin_amdgcn_s_barrier();
    }

#pragma unroll
    for (int i = 0; i < 2; ++i)
#pragma unroll
        for (int r = 0; r < 4; ++r) {
            int m = bm + wr * 32 + i * 16 + quad * 4 + r;
#pragma unroll
            for (int j = 0; j < 12; ++j) {
                int n = n0 + wc * 192 + j * 16 + l16;
                float v = acc[i][j][r] + bias[n];
                if (RELU) v = fmaxf(v, 0.0f);
                if (ACCUM) {
                    float* o = &((float*)out_)[(size_t)m * NFULL + n];
                    *o = *o + v;
                } else {
                    ((__bf16*)out_)[(size_t)m * NFULL + n] = (__bf16)v;
                }
            }
        }
}

// ---------------- Pipelined GEMM v3 (3-buffer, counted vmcnt): out = A @ Bt^T --------
// TM=128 x TN=192, 512 thr = 8 waves (4x2), BK=64, TRIPLE-buffered 120 KB LDS,
// 1 block/CU. r10 lesson: 2-buffer designs drain vmcnt(0) every tile -> each tile pays
// the tail latency of its own loads. Here 2 tiles stay in flight: per tile only
// vmcnt(5) (5 = per-wave loads/stage) before the barrier, so the NEXT tile's loads
// keep flying across it (T4, m218). Drain to 0 only on the last tile.
// Overwrite safety: stage(kt+2) targets b[(kt-1)%3] and is issued after barrier kt,
// by which point every wave finished computing tile kt-1 (ds_read data is in regs via
// compiler lgkm waits before the MFMAs, which precede the barrier in program order).
// 128-B-row XOR swizzle unchanged (0 conflicts, r6/r9/r10). Bijective XCD swizzle
// (T1, m204 formula; nwg%8==0) so n-block pairs sharing an A panel land on the same
// XCD -> second A read hits that XCD's L2.
template <int K, int NFULL, int GX, bool RELU, bool ACCUM>
__global__ __launch_bounds__(512, 1) void gemm_pipe3(const __bf16* __restrict__ A,
                                                     const __bf16* __restrict__ Bt,   // [NFULL,K]
                                                     const float* __restrict__ bias,
                                                     void* __restrict__ out_) {
    constexpr int NT = K / BK;                 // 6 or 24 (divisible by 3)
    __shared__ __align__(16) __bf16 At[3][128 * 64];   // 48 KB
    __shared__ __align__(16) __bf16 Bs[3][192 * 64];   // 72 KB

    int tid = threadIdx.x;
    int wave = tid >> 6, lane = tid & 63;
    int wr = wave >> 1, wc = wave & 1;         // 4x2 wave grid; each wave: 32 rows x 96 cols
    int quad = lane >> 4, l16 = lane & 15;

    // XCD-bijective block swizzle (nwg = GX*256, multiple of 8)
    constexpr int NWG = GX * (M_ROWS / 128);
    int lin = blockIdx.x + blockIdx.y * GX;
    int swz = (lin & 7) * (NWG / 8) + (lin >> 3);
    int bm = (swz / GX) * 128;
    int n0 = (swz % GX) * 192;

    int srow = lane >> 3;                      // row within 8-row group
    int sunit = (lane & 7) ^ srow;             // pre-swizzled source 16-B unit

    const __bf16* asrc0 = A + (size_t)(bm + srow) * K + sunit * 8;
    const __bf16* bsrc0 = Bt + (size_t)(n0 + srow) * K + sunit * 8;

    // stage one BK-tile (40 KB): per wave 2 A + 3 B gload_lds (1 KB each) -> L = 5
    auto stage = [&](int buf, int k0) {
#pragma unroll
        for (int t = 0; t < 2; ++t) {
            int g = t * 8 + wave;              // 8-row group 0..15 (128 A rows)
            load16_lds(asrc0 + (size_t)(g * 8) * K + k0, &At[buf][g * 8 * 64]);
        }
#pragma unroll
        for (int t = 0; t < 3; ++t) {
            int g = t * 8 + wave;              // 8-row group 0..23 (192 B rows)
            load16_lds(bsrc0 + (size_t)(g * 8) * K + k0, &Bs[buf][g * 8 * 64]);
        }
    };

    f32x4 acc[2][6] = {};

    auto compute = [&](int cb) {
        bf16_8 af[2][2];
#pragma unroll
        for (int p = 0; p < 2; ++p)
#pragma unroll
            for (int i = 0; i < 2; ++i) {
                int row = wr * 32 + i * 16 + l16;
                int u = (p * 4 + quad) ^ (row & 7);   // k = p*32 + quad*8
                af[i][p] = *reinterpret_cast<const bf16_8*>(&At[cb][row * 64 + u * 8]);
            }
#pragma unroll
        for (int p = 0; p < 2; ++p)
#pragma unroll
            for (int j = 0; j < 6; ++j) {
                int row = wc * 96 + j * 16 + l16;
                int u = (p * 4 + quad) ^ (row & 7);
                bf16_8 bf = *reinterpret_cast<const bf16_8*>(&Bs[cb][row * 64 + u * 8]);
                acc[0][j] = __builtin_amdgcn_mfma_f32_16x16x32_bf16(af[0][p], bf, acc[0][j], 0, 0, 0);
                acc[1][j] = __builtin_amdgcn_mfma_f32_16x16x32_bf16(af[1][p], bf, acc[1][j], 0, 0, 0);
            }
    };

    // prologue: 2 tiles in flight
    stage(0, 0);
    stage(1, BK);

    // main loop: counted wait keeps tile kt+1's loads flying across the barrier
    for (int kt = 0; kt < NT - 2; ++kt) {
        asm volatile("s_waitcnt vmcnt(5)" ::: "memory");   // tile kt complete (own 5)
        __builtin_amdgcn_sched_barrier(0);
        __builtin_amdgcn_s_barrier();                      // all waves' tile-kt loads landed
        stage((kt + 2) % 3, (kt + 2) * BK);                // overwrites b[(kt-1)%3]: safe
        compute(kt % 3);
    }
    // kt = NT-2: tile NT-1 still in flight
    asm volatile("s_waitcnt vmcnt(5)" ::: "memory");
    __builtin_amdgcn_sched_barrier(0);
    __builtin_amdgcn_s_barrier();
    compute((NT - 2) % 3);
    // kt = NT-1: final drain
    asm volatile("s_waitcnt vmcnt(0)" ::: "memory");
    __builtin_amdgcn_sched_barrier(0);
    __builtin_amdgcn_s_barrier();
    compute((NT - 1) % 3);

    // epilogue (C/D layout: col=l16, row=quad*4+r); n-blocks disjoint -> one writer/elem
#pragma unroll
    for (int i = 0; i < 2; ++i)
#pragma unroll
        for (int r = 0; r < 4; ++r) {
            int m = bm + wr * 32 + i * 16 + quad * 4 + r;
#pragma unroll
            for (int j = 0; j < 6; ++j) {
                int n = n0 + wc * 96 + j * 16 + l16;
                float v = acc[i][j][r] + bias[n];
                if (RELU) v = fmaxf(v, 0.0f);
                if (ACCUM) {
                    float* o = &((float*)out_)[(size_t)m * NFULL + n];
                    *o = *o + v;
                } else {
                    ((__bf16*)out_)[(size_t)m * NFULL + n] = (__bf16)v;
                }
            }
        }
}

// ---------------- Fused proj GEMM + residual + LN2 ------------------------------------
// out = x + yb @ Wp^T + b_proj ; h = bf16(LN(out)). TM=64 x TN=384 (full row) so each
// block owns complete rows -> LN reduction in-epilogue (shfl over l16, LDS across wc).
__global__ __launch_bounds__(256) void proj_ln_kernel(const __bf16* __restrict__ A,     // yb [M,384]
                                                      const __bf16* __restrict__ Bt,    // Wproj_t [384,384]
                                                      const float* __restrict__ bias,   // b_proj
                                                      const float* __restrict__ resid,  // x
                                                      const float* __restrict__ lng,
                                                      const float* __restrict__ lnb,
                                                      float* __restrict__ out,          // fp32 [M,384]
                                                      __bf16* __restrict__ h) {         // bf16 [M,384]
    __shared__ __align__(16) __bf16 As[2 * 64 * 32];    // 8 KB
    __shared__ __align__(16) __bf16 Bs[2 * 384 * 32];   // 48 KB
    __shared__ float red[2][2][64];                     // [sum|sumsq][wc][row]

    int tid = threadIdx.x;
    int wave = tid >> 6, lane = tid & 63;
    int wr = wave >> 1, wc = wave & 1;
    int quad = lane >> 4, l16 = lane & 15;
    int bm = blockIdx.x * 64;
    int lrow = lane >> 2, lcol = (lane & 3) * 8;

    f32x4 acc[2][12] = {};

    for (int k0 = 0; k0 < C_EMB; k0 += BK) {
        const __bf16* Ab = A + (size_t)bm * C_EMB + k0;
        const __bf16* Bb = Bt + k0;
#pragma unroll
        for (int p = 0; p < 2; ++p) {
            {   // A: 64 rows, one 16-row group per wave
                int r0 = wave * 16;
                load16_lds(Ab + (size_t)(r0 + lrow) * C_EMB + p * 32 + lcol,
                           &As[p * 64 * 32 + r0 * 32]);
            }
#pragma unroll
            for (int i = 0; i < 6; ++i) {   // B: 384 rows
                int r0 = (i * 4 + wave) * 16;
                load16_lds(Bb + (size_t)(r0 + lrow) * C_EMB + p * 32 + lcol,
                           &Bs[p * 384 * 32 + r0 * 32]);
            }
        }
        __syncthreads();

        bf16_8 af[2][2], bf[12][2];
#pragma unroll
        for (int p = 0; p < 2; ++p) {
#pragma unroll
            for (int i = 0; i < 2; ++i)
                af[i][p] = *reinterpret_cast<const bf16_8*>(
                    &As[p * 64 * 32 + (wr * 32 + i * 16 + l16) * 32 + quad * 8]);
#pragma unroll
            for (int j = 0; j < 12; ++j)
                bf[j][p] = *reinterpret_cast<const bf16_8*>(
                    &Bs[p * 384 * 32 + (wc * 192 + j * 16 + l16) * 32 + quad * 8]);
        }
#pragma unroll
        for (int i = 0; i < 2; ++i)
#pragma unroll
            for (int j = 0; j < 12; ++j) {
                acc[i][j] = __builtin_amdgcn_mfma_f32_16x16x32_bf16(af[i][0], bf[j][0], acc[i][j], 0, 0, 0);
                acc[i][j] = __builtin_amdgcn_mfma_f32_16x16x32_bf16(af[i][1], bf[j][1], acc[i][j], 0, 0, 0);
            }
        __syncthreads();
    }

    // per-thread column constants (same cols for every row this thread touches)
    float bia[12], gg[12], bb[12];
#pragma unroll
    for (int j = 0; j < 12; ++j) {
        int n = wc * 192 + j * 16 + l16;
        bia[j] = bias[n];
        gg[j] = lng[n];
        bb[j] = lnb[n];
    }

    // pass 1: v = acc + bias + resid (in-place), row sum & sumsq -> red
#pragma unroll
    for (int i = 0; i < 2; ++i)
#pragma unroll
        for (int r = 0; r < 4; ++r) {
            int rloc = wr * 32 + i * 16 + quad * 4 + r;
            int m = bm + rloc;
            float s = 0.0f, s2 = 0.0f;
#pragma unroll
            for (int j = 0; j < 12; ++j) {
                int n = wc * 192 + j * 16 + l16;
                float v = acc[i][j][r] + bia[j] + resid[(size_t)m * C_EMB + n];
                acc[i][j][r] = v;
                s += v;
                s2 += v * v;
            }
#pragma unroll
            for (int o = 8; o; o >>= 1) {
                s += __shfl_xor(s, o);
                s2 += __shfl_xor(s2, o);
            }
            if (l16 == 0) {
                red[0][wc][rloc] = s;
                red[1][wc][rloc] = s2;
            }
        }
    __syncthreads();

    // pass 2: normalize + write out (fp32) and h (bf16 LN)
#pragma unroll
    for (int i = 0; i < 2; ++i)
#pragma unroll
        for (int r = 0; r < 4; ++r) {
            int rloc = wr * 32 + i * 16 + quad * 4 + r;
            int m = bm + rloc;
            float mu  = (red[0][0][rloc] + red[0][1][rloc]) * (1.0f / C_EMB);
            float ex2 = (red[1][0][rloc] + red[1][1][rloc]) * (1.0f / C_EMB);
            float rstd = rsqrtf(ex2 - mu * mu + 1e-5f);
#pragma unroll
            for (int j = 0; j < 12; ++j) {
                int n = wc * 192 + j * 16 + l16;
                float v = acc[i][j][r];
                out[(size_t)m * C_EMB + n] = v;
                h[(size_t)m * C_EMB + n] = (__bf16)((v - mu) * rstd * gg[j] + bb[j]);
            }
        }
}

// ---------------- V transpose: Vt[b][c][s] = qkv[b][s][768+c] -------------------------
__global__ __launch_bounds__(256) void vt_kernel(const __bf16* __restrict__ qkv,
                                                 __bf16* __restrict__ Vt) {
    __shared__ __align__(16) __bf16 t[32][72];
    int b = blockIdx.z, c0 = blockIdx.x * 64, s0 = blockIdx.y * 32;
    int tid = threadIdx.x;

    int tx = tid & 7, ty = tid >> 3;
    const __bf16* src = qkv + ((size_t)b * T_SEQ + s0 + ty) * QKV_LD + 768 + c0 + tx * 8;
    *reinterpret_cast<float4*>(&t[ty][tx * 8]) = *reinterpret_cast<const float4*>(src);
    __syncthreads();

    int sx = tid & 3, cy = tid >> 2;
    __align__(16) __bf16 tmp[8];
#pragma unroll
    for (int j = 0; j < 8; ++j) tmp[j] = t[sx * 8 + j][cy];
    *reinterpret_cast<float4*>(&Vt[((size_t)b * C_EMB + c0 + cy) * T_SEQ + s0 + sx * 8]) =
        *reinterpret_cast<float4*>(tmp);
}

// ---------------- Fused QK^T + causal softmax: P = softmax(scale*Q@K^T) ---------------
// Grid (2, B): bx=0 -> q-rows [0,128), 1 k-tile; bx=1 -> q-rows [128,256), 2 k-tiles.
// nt loop statically unrolled with block-uniform guard (rule #20: acc must stay
// compile-time indexed or it spills to scratch — round-3 regression).
__global__ __launch_bounds__(256) void qks_mfma(const __bf16* __restrict__ qkv,
                                                __bf16* __restrict__ P) {
    int b = blockIdx.y;
    int bx = blockIdx.x;
    int bm = bx * 128;
    int ntiles = bx + 1;
    const __bf16* Ab0 = qkv + (size_t)b * T_SEQ * QKV_LD;
    const __bf16* Bb0 = Ab0 + 384;

    __shared__ __align__(16) __bf16 As[2 * 128 * 32];
    __shared__ __align__(16) __bf16 Bs[2 * 128 * 32];
    __shared__ float red[2][2][128];   // [max|sum][wc][local row]

    int tid = threadIdx.x;
    int wave = tid >> 6, lane = tid & 63;
    int wr = wave >> 1, wc = wave & 1;
    int quad = lane >> 4, l16 = lane & 15;
    int lrow = lane >> 2, lcol = (lane & 3) * 8;

    f32x4 acc[2][4][4] = {};

#pragma unroll
    for (int nt = 0; nt < 2; ++nt) {
        if (nt < ntiles) {                      // block-uniform guard
            int bn = nt * 128;
            for (int k0 = 0; k0 < C_EMB; k0 += BK) {
                const __bf16* Ab = Ab0 + (size_t)bm * QKV_LD + k0;
                const __bf16* Bb = Bb0 + (size_t)bn * QKV_LD + k0;
#pragma unroll
                for (int p = 0; p < 2; ++p)
#pragma unroll
                    for (int i = 0; i < 2; ++i) {
                        int r0 = (i * 4 + wave) * 16;
                        load16_lds(Ab + (size_t)(r0 + lrow) * QKV_LD + p * 32 + lcol,
                                   &As[p * 128 * 32 + r0 * 32]);
                        load16_lds(Bb + (size_t)(r0 + lrow) * QKV_LD + p * 32 + lcol,
                                   &Bs[p * 128 * 32 + r0 * 32]);
                    }
                __syncthreads();

                bf16_8 af[4][2], bf[4][2];
#pragma unroll
                for (int p = 0; p < 2; ++p)
#pragma unroll
                    for (int i = 0; i < 4; ++i) {
                        af[i][p] = *reinterpret_cast<const bf16_8*>(
                            &As[p * 128 * 32 + (wr * 64 + i * 16 + l16) * 32 + quad * 8]);
                        bf[i][p] = *reinterpret_cast<const bf16_8*>(
                            &Bs[p * 128 * 32 + (wc * 64 + i * 16 + l16) * 32 + quad * 8]);
                    }
#pragma unroll
                for (int i = 0; i < 4; ++i)
#pragma unroll
                    for (int j = 0; j < 4; ++j) {
                        acc[nt][i][j] = __builtin_amdgcn_mfma_f32_16x16x32_bf16(af[i][0], bf[j][0], acc[nt][i][j], 0, 0, 0);
                        acc[nt][i][j] = __builtin_amdgcn_mfma_f32_16x16x32_bf16(af[i][1], bf[j][1], acc[nt][i][j], 0, 0, 0);
                    }
                __syncthreads();
            }
        }
    }

    // ---- softmax epilogue (fp32 in-register) ----
    const float scale = 0.05103103630798288f;

    // 1) per-row max: local (nt,j) -> shfl over l16 -> LDS across the 2 wc-waves
#pragma unroll
    for (int i = 0; i < 4; ++i)
#pragma unroll
        for (int r = 0; r < 4; ++r) {
            int rloc = wr * 64 + i * 16 + quad * 4 + r;
            int t = bm + rloc;
            float m = -INFINITY;
#pragma unroll
            for (int nt = 0; nt < 2; ++nt)
#pragma unroll
                for (int j = 0; j < 4; ++j) {
                    int n = nt * 128 + wc * 64 + j * 16 + l16;
                    bool ok = (nt < ntiles) && (n <= t);
                    float v = acc[nt][i][j][r] * scale;
                    m = fmaxf(m, ok ? v : -INFINITY);
                }
#pragma unroll
            for (int o = 8; o; o >>= 1) m = fmaxf(m, __shfl_xor(m, o));
            if (l16 == 0) red[0][wc][rloc] = m;
        }
    __syncthreads();

    // 2) exp + per-row sum (same reduction path); p values overwrite acc
#pragma unroll
    for (int i = 0; i < 4; ++i)
#pragma unroll
        for (int r = 0; r < 4; ++r) {
            int rloc = wr * 64 + i * 16 + quad * 4 + r;
            int t = bm + rloc;
            float M = fmaxf(red[0][0][rloc], red[0][1][rloc]);
            float s = 0.0f;
#pragma unroll
            for (int nt = 0; nt < 2; ++nt)
#pragma unroll
                for (int j = 0; j < 4; ++j) {
                    int n = nt * 128 + wc * 64 + j * 16 + l16;
                    bool ok = (nt < ntiles) && (n <= t);
                    float p = ok ? __expf(acc[nt][i][j][r] * scale - M) : 0.0f;
                    acc[nt][i][j][r] = p;
                    s += p;
                }
#pragma unroll
            for (int o = 8; o; o >>= 1) s += __shfl_xor(s, o);
            if (l16 == 0) red[1][wc][rloc] = s;
        }
    __syncthreads();

    // 3) normalize + write bf16 P (only the tiles this block owns; pv never reads the rest)
    __bf16* Pb_ = P + (size_t)b * T_SEQ * T_SEQ;
#pragma unroll
    for (int i = 0; i < 4; ++i)
#pragma unroll
        for (int r = 0; r < 4; ++r) {
            int rloc = wr * 64 + i * 16 + quad * 4 + r;
            float inv = 1.0f / (red[1][0][rloc] + red[1][1][rloc]);
#pragma unroll
            for (int nt = 0; nt < 2; ++nt)
                if (nt < ntiles)
#pragma unroll
                    for (int j = 0; j < 4; ++j) {
                        int n = nt * 128 + wc * 64 + j * 16 + l16;
                        Pb_[(size_t)(bm + rloc) * T_SEQ + n] = (__bf16)(acc[nt][i][j][r] * inv);
                    }
        }
}

// ---------------- Attention pass 3: y = P @ V (MFMA, causal k-skip) -------------------
__global__ __launch_bounds__(256) void pv_mfma(const __bf16* __restrict__ P,
                                               const __bf16* __restrict__ Vt,
                                               __bf16* __restrict__ y) {
    int b = blockIdx.z;
    int bm = blockIdx.y * 128, bn = blockIdx.x * 128;
    const __bf16* Ab0 = P + (size_t)b * T_SEQ * T_SEQ;
    const __bf16* Bb0 = Vt + (size_t)b * C_EMB * T_SEQ;

    __shared__ __align__(16) __bf16 As[2 * 128 * 32];
    __shared__ __align__(16) __bf16 Bs[2 * 128 * 32];

    int tid = threadIdx.x;
    int wave = tid >> 6, lane = tid & 63;
    int wr = wave >> 1, wc = wave & 1;
    int quad = lane >> 4, l16 = lane & 15;
    int lrow = lane >> 2, lcol = (lane & 3) * 8;

    f32x4 acc[4][4] = {};

    int kmax = bm + 128;   // divisible by 64
    for (int k0 = 0; k0 < kmax; k0 += BK) {
        const __bf16* Ab = Ab0 + (size_t)bm * T_SEQ + k0;
        const __bf16* Bb = Bb0 + (size_t)bn * T_SEQ + k0;
#pragma unroll
        for (int p = 0; p < 2; ++p)
#pragma unroll
            for (int i = 0; i < 2; ++i) {
                int r0 = (i * 4 + wave) * 16;
                load16_lds(Ab + (size_t)(r0 + lrow) * T_SEQ + p * 32 + lcol,
                           &As[p * 128 * 32 + r0 * 32]);
                load16_lds(Bb + (size_t)(r0 + lrow) * T_SEQ + p * 32 + lcol,
                           &Bs[p * 128 * 32 + r0 * 32]);
            }
        __syncthreads();

        bf16_8 af[4][2], bf[4][2];
#pragma unroll
        for (int p = 0; p < 2; ++p)
#pragma unroll
            for (int i = 0; i < 4; ++i) {
                af[i][p] = *reinterpret_cast<const bf16_8*>(
                    &As[p * 128 * 32 + (wr * 64 + i * 16 + l16) * 32 + quad * 8]);
                bf[i][p] = *reinterpret_cast<const bf16_8*>(
                    &Bs[p * 128 * 32 + (wc * 64 + i * 16 + l16) * 32 + quad * 8]);
            }
#pragma unroll
        for (int i = 0; i < 4; ++i)
#pragma unroll
            for (int j = 0; j < 4; ++j) {
                acc[i][j] = __builtin_amdgcn_mfma_f32_16x16x32_bf16(af[i][0], bf[j][0], acc[i][j], 0, 0, 0);
                acc[i][j] = __builtin_amdgcn_mfma_f32_16x16x32_bf16(af[i][1], bf[j][1], acc[i][j], 0, 0, 0);
            }
        __syncthreads();
    }

#pragma unroll
    for (int i = 0; i < 4; ++i) {
#pragma unroll
        for (int r = 0; r < 4; ++r) {
            int m = bm + wr * 64 + i * 16 + quad * 4 + r;
#pragma unroll
            for (int j = 0; j < 4; ++j) {
                int n = bn + wc * 64 + j * 16 + l16;
                y[((size_t)b * T_SEQ + m) * C_EMB + n] = (__bf16)acc[i][j][r];
            }
        }
    }
}

extern "C" void kernel_launch(void* const* d_in, const int* in_sizes, int n_in,
                              void* d_out, int out_size, void* d_ws, size_t ws_size,
                              hipStream_t stream) {
    const float* x      = (const float*)d_in[0];
    const float* W_attn = (const float*)d_in[1];
    const float* b_attn = (const float*)d_in[2];
    const float* W_proj = (const float*)d_in[3];
    const float* b_proj = (const float*)d_in[4];
    const float* ln1_g  = (const float*)d_in[5];
    const float* ln1_b  = (const float*)d_in[6];
    const float* ln2_g  = (const float*)d_in[7];
    const float* ln2_b  = (const float*)d_in[8];
    const float* W1     = (const float*)d_in[9];
    const float* b1     = (const float*)d_in[10];
    const float* W2     = (const float*)d_in[11];
    const float* b2     = (const float*)d_in[12];
    float* out = (float*)d_out;

    // ---- workspace (205 MB; ws >= 251.6 MB proven) ----
    __bf16* Wattn_t = (__bf16*)d_ws;                            // [1152,384]
    __bf16* Wproj_t = Wattn_t + (size_t)1152 * 384;             // [384,384]
    __bf16* W1_t    = Wproj_t + (size_t)384 * 384;              // [1536,384]
    __bf16* W2_t    = W1_t + (size_t)1536 * 384;                // [384,1536]
    __bf16* h       = W2_t + (size_t)384 * 1536;                // [M,384] bf16
    __bf16* yb      = h + (size_t)M_ROWS * 384;                 // [M,384] bf16
    __bf16* qkv     = yb + (size_t)M_ROWS * 384;                // [M,1152] bf16
    float*  S       = (float*)(qkv + (size_t)M_ROWS * QKV_LD);  // [B,T,T] fp32 (unused, layout kept)
    __bf16* Pb      = (__bf16*)(S + (size_t)B_BATCH * T_SEQ * T_SEQ);  // [B,T,T] bf16
    __bf16* Vt      = Pb + (size_t)B_BATCH * T_SEQ * T_SEQ;     // [B,384,T] bf16
    __bf16* ff      = qkv;                                      // [M,1536] bf16 alias

    // 0. weights → bf16 [N,K], one dispatch (432+144+576+576 = 1728 tiles)
    cast_all_kernel<<<1728, 256, 0, stream>>>(W_attn, W_proj, W1, W2,
                                              Wattn_t, Wproj_t, W1_t, W2_t);

    // 1. h = bf16(LN1(x))
    ln_kernel<<<M_ROWS, 384, 0, stream>>>(x, ln1_g, ln1_b, h);
    // 2. qkv = bf16(h @ W_attn + b_attn)   (pipelined, r9-proven TN=384)
    gemm_pipe<384, 1152, false, false><<<dim3(1152 / 384, M_ROWS / 128), 512, 0, stream>>>(
        h, Wattn_t, b_attn, qkv);
    // 3. attention (bf16 MFMA core; QK^T + causal softmax fused)
    vt_kernel<<<dim3(C_EMB / 64, T_SEQ / 32, B_BATCH), 256, 0, stream>>>(qkv, Vt);
    qks_mfma<<<dim3(2, B_BATCH), 256, 0, stream>>>(qkv, Pb);
    pv_mfma<<<dim3(C_EMB / 128, T_SEQ / 128, B_BATCH), 256, 0, stream>>>(Pb, Vt, yb);
    // 4+5. out = x + yb @ W_proj + b_proj ; h = bf16(LN2(out))   (fused)
    proj_ln_kernel<<<M_ROWS / 64, 256, 0, stream>>>(yb, Wproj_t, b_proj, x,
                                                    ln2_g, ln2_b, out, h);
    // 6. ff = bf16(relu(h2 @ W1 + b1))   (3-buffer counted-vmcnt pipeline + XCD swizzle)
    gemm_pipe3<384, 1536, 8, true, false><<<dim3(1536 / 192, M_ROWS / 128), 512, 0, stream>>>(
        h, W1_t, b1, ff);
    // 7. out += ff @ W2 + b2   (3-buffer counted-vmcnt pipeline + XCD swizzle)
    gemm_pipe3<1536, 384, 2, false, true><<<dim3(384 / 192, M_ROWS / 128), 512, 0, stream>>>(
        ff, W2_t, b2, out);
}

// Round 12
// 415.101 us; speedup vs baseline: 1.0859x; 1.0859x over previous
//
#include <hip/hip_runtime.h>
#include <hip/hip_bf16.h>

#define C_EMB 384
#define T_SEQ 256
#define B_BATCH 128
#define M_ROWS (B_BATCH * T_SEQ)   // 32768
#define QKV_LD 1152                // row stride of qkv buffer (bf16)
#define BK 64                      // K-tile = two 32-elem panels (each 64-B rows, m97 layout)

typedef __bf16 bf16_8 __attribute__((ext_vector_type(8)));
typedef float f32x4 __attribute__((ext_vector_type(4)));

// Async global->LDS 16-B copy. Dest is wave-uniform base + lane*16 (m104/m108).
__device__ __forceinline__ void load16_lds(const __bf16* g, __bf16* l) {
    __builtin_amdgcn_global_load_lds(
        (const __attribute__((address_space(1))) unsigned int*)g,
        (__attribute__((address_space(3))) unsigned int*)l, 16, 0, 0);
}

// ---------------- All-weights cast + transpose (single dispatch) ----------------------
// Wt[n][k] = bf16(W[k][n]) for the 4 weight matrices; block ranges select the matrix.
__global__ __launch_bounds__(256) void cast_all_kernel(const float* __restrict__ Wa,
                                                       const float* __restrict__ Wp,
                                                       const float* __restrict__ W1,
                                                       const float* __restrict__ W2,
                                                       __bf16* __restrict__ Wa_t,
                                                       __bf16* __restrict__ Wp_t,
                                                       __bf16* __restrict__ W1_t,
                                                       __bf16* __restrict__ W2_t) {
    int bid = blockIdx.x;
    const float* W; __bf16* Wt; int K, N, tx_n;
    // tile counts: Wa 36x12=432, Wp 12x12=144, W1 48x12=576, W2 12x48=576
    if (bid < 432)      { W = Wa; Wt = Wa_t; K = 384;  N = 1152; tx_n = 36; }
    else if (bid < 576) { bid -= 432; W = Wp; Wt = Wp_t; K = 384;  N = 384;  tx_n = 12; }
    else if (bid < 1152){ bid -= 576; W = W1; Wt = W1_t; K = 384;  N = 1536; tx_n = 48; }
    else                { bid -= 1152; W = W2; Wt = W2_t; K = 1536; N = 384;  tx_n = 12; }
    int n0 = (bid % tx_n) * 32, k0 = (bid / tx_n) * 32;

    __shared__ float t[32][33];
    int tx = threadIdx.x & 31, ty = threadIdx.x >> 5;
#pragma unroll
    for (int i = 0; i < 4; ++i)
        t[ty + i * 8][tx] = W[(size_t)(k0 + ty + i * 8) * N + n0 + tx];
    __syncthreads();
#pragma unroll
    for (int i = 0; i < 4; ++i) {
        int n = ty + i * 8;
        Wt[(size_t)(n0 + n) * K + k0 + tx] = (__bf16)t[tx][n];
    }
}

// ---------------- LayerNorm: one block (384 threads) per row, bf16 out ----------------
__global__ __launch_bounds__(384) void ln_kernel(const float* __restrict__ x,
                                                 const float* __restrict__ g,
                                                 const float* __restrict__ bta,
                                                 __bf16* __restrict__ out) {
    int row = blockIdx.x;
    int c = threadIdx.x;
    float v = x[(size_t)row * C_EMB + c];

    __shared__ float red[6];
    float s = v;
#pragma unroll
    for (int o = 32; o; o >>= 1) s += __shfl_down(s, o);
    if ((c & 63) == 0) red[c >> 6] = s;
    __syncthreads();
    float mu = (red[0] + red[1] + red[2] + red[3] + red[4] + red[5]) * (1.0f / C_EMB);

    float d = v - mu;
    float s2 = d * d;
#pragma unroll
    for (int o = 32; o; o >>= 1) s2 += __shfl_down(s2, o);
    __syncthreads();
    if ((c & 63) == 0) red[c >> 6] = s2;
    __syncthreads();
    float var = (red[0] + red[1] + red[2] + red[3] + red[4] + red[5]) * (1.0f / C_EMB);

    out[(size_t)row * C_EMB + c] = (__bf16)(d * rsqrtf(var + 1e-5f) * g[c] + bta[c]);
}

// ---------------- Pipelined GEMM v2 (2 blocks/CU, XCD-swizzled) ----------------------
// TM=128 x TN=192, 256 thr = 4 waves, BK=64, double-buffered 80 KB LDS -> 2 blocks/CU.
// r10-proven structure (ff2 70 µs): stage-at-top, ds_read+MFMA, ONE vmcnt(0) + raw
// s_barrier per tile. 128-B-row XOR swizzle (rule #21; 0 conflicts r6/r9/r10):
// LDS[row][u] = G[row][u^(row&7)], read u=(p*4+quad)^(row&7) -> k = p*32+quad*8.
// r11 lesson: 2 independent barrier domains/CU beat 1-block deeper pipelines — what
// pays on these small-K GEMMs is per-CU concurrency, not pipeline depth.
// NEW (from r11, the one piece that verifiably worked): bijective XCD block swizzle
// (FETCH 125->83 MB on ff2) — each XCD gets a contiguous bm range with ALL its
// n-blocks, so A-panel re-reads hit that XCD's L2. Bijective since NWG%8==0 (m204).
template <int K, int NFULL, int GX, bool RELU, bool ACCUM>
__global__ __launch_bounds__(256, 2) void gemm_pipe2(const __bf16* __restrict__ A,
                                                     const __bf16* __restrict__ Bt,   // [NFULL,K]
                                                     const float* __restrict__ bias,
                                                     void* __restrict__ out_) {
    __shared__ __align__(16) __bf16 At[2][128 * 64];   // 32 KB
    __shared__ __align__(16) __bf16 Bs[2][192 * 64];   // 48 KB

    int tid = threadIdx.x;
    int wave = tid >> 6, lane = tid & 63;     // 4 waves, each owns 32 rows x 192 cols
    int quad = lane >> 4, l16 = lane & 15;

    // XCD-bijective block swizzle (nwg = GX*256, multiple of 8)
    constexpr int NWG = GX * (M_ROWS / 128);
    int lin = blockIdx.x + blockIdx.y * GX;
    int swz = (lin & 7) * (NWG / 8) + (lin >> 3);
    int bm = (swz / GX) * 128;
    int n0 = (swz % GX) * 192;

    int srow = lane >> 3;                     // row within 8-row group
    int sunit = (lane & 7) ^ srow;            // pre-swizzled source 16-B unit

    const __bf16* asrc0 = A + (size_t)(bm + srow) * K + sunit * 8;
    const __bf16* bsrc0 = Bt + (size_t)(n0 + srow) * K + sunit * 8;

    // stage one BK-tile: per wave 4 A + 6 B gload_lds (1 KB each, 40 KB/block)
    auto stage = [&](int buf, int k0) {
#pragma unroll
        for (int t = 0; t < 4; ++t) {
            int g = t * 4 + wave;             // 8-row group 0..15 (128 A rows)
            load16_lds(asrc0 + (size_t)(g * 8) * K + k0, &At[buf][g * 8 * 64]);
        }
#pragma unroll
        for (int t = 0; t < 6; ++t) {
            int g = t * 4 + wave;             // 8-row group 0..23 (192 B rows)
            load16_lds(bsrc0 + (size_t)(g * 8) * K + k0, &Bs[buf][g * 8 * 64]);
        }
    };

    f32x4 acc[2][12] = {};

    stage(0, 0);
    asm volatile("s_waitcnt vmcnt(0)" ::: "memory");
    __builtin_amdgcn_sched_barrier(0);
    __builtin_amdgcn_s_barrier();

#pragma unroll 2
    for (int kt = 0; kt < K / BK; ++kt) {
        int cur = kt & 1;
        if (kt < K / BK - 1) stage(cur ^ 1, (kt + 1) * BK);   // issue next-tile loads FIRST

        bf16_8 af[2][2];
#pragma unroll
        for (int p = 0; p < 2; ++p)
#pragma unroll
            for (int i = 0; i < 2; ++i) {
                int row = wave * 32 + i * 16 + l16;
                int u = (p * 4 + quad) ^ (row & 7);   // k = p*32 + quad*8
                af[i][p] = *reinterpret_cast<const bf16_8*>(&At[cur][row * 64 + u * 8]);
            }
#pragma unroll
        for (int p = 0; p < 2; ++p)
#pragma unroll
            for (int j = 0; j < 12; ++j) {
                int row = j * 16 + l16;
                int u = (p * 4 + quad) ^ (row & 7);
                bf16_8 bf = *reinterpret_cast<const bf16_8*>(&Bs[cur][row * 64 + u * 8]);
                acc[0][j] = __builtin_amdgcn_mfma_f32_16x16x32_bf16(af[0][p], bf, acc[0][j], 0, 0, 0);
                acc[1][j] = __builtin_amdgcn_mfma_f32_16x16x32_bf16(af[1][p], bf, acc[1][j], 0, 0, 0);
            }

        asm volatile("s_waitcnt vmcnt(0)" ::: "memory");
        __builtin_amdgcn_sched_barrier(0);
        __builtin_amdgcn_s_barrier();
    }

    // epilogue (C/D layout: col=l16, row=quad*4+r); n-blocks disjoint -> one writer/elem
#pragma unroll
    for (int i = 0; i < 2; ++i)
#pragma unroll
        for (int r = 0; r < 4; ++r) {
            int m = bm + wave * 32 + i * 16 + quad * 4 + r;
#pragma unroll
            for (int j = 0; j < 12; ++j) {
                int n = n0 + j * 16 + l16;
                float v = acc[i][j][r] + bias[n];
                if (RELU) v = fmaxf(v, 0.0f);
                if (ACCUM) {
                    float* o = &((float*)out_)[(size_t)m * NFULL + n];
                    *o = *o + v;
                } else {
                    ((__bf16*)out_)[(size_t)m * NFULL + n] = (__bf16)v;
                }
            }
        }
}

// ---------------- Fused proj GEMM + residual + LN2 ------------------------------------
// out = x + yb @ Wp^T + b_proj ; h = bf16(LN(out)). TM=64 x TN=384 (full row) so each
// block owns complete rows -> LN reduction in-epilogue (shfl over l16, LDS across wc).
__global__ __launch_bounds__(256) void proj_ln_kernel(const __bf16* __restrict__ A,     // yb [M,384]
                                                      const __bf16* __restrict__ Bt,    // Wproj_t [384,384]
                                                      const float* __restrict__ bias,   // b_proj
                                                      const float* __restrict__ resid,  // x
                                                      const float* __restrict__ lng,
                                                      const float* __restrict__ lnb,
                                                      float* __restrict__ out,          // fp32 [M,384]
                                                      __bf16* __restrict__ h) {         // bf16 [M,384]
    __shared__ __align__(16) __bf16 As[2 * 64 * 32];    // 8 KB
    __shared__ __align__(16) __bf16 Bs[2 * 384 * 32];   // 48 KB
    __shared__ float red[2][2][64];                     // [sum|sumsq][wc][row]

    int tid = threadIdx.x;
    int wave = tid >> 6, lane = tid & 63;
    int wr = wave >> 1, wc = wave & 1;
    int quad = lane >> 4, l16 = lane & 15;
    int bm = blockIdx.x * 64;
    int lrow = lane >> 2, lcol = (lane & 3) * 8;

    f32x4 acc[2][12] = {};

    for (int k0 = 0; k0 < C_EMB; k0 += BK) {
        const __bf16* Ab = A + (size_t)bm * C_EMB + k0;
        const __bf16* Bb = Bt + k0;
#pragma unroll
        for (int p = 0; p < 2; ++p) {
            {   // A: 64 rows, one 16-row group per wave
                int r0 = wave * 16;
                load16_lds(Ab + (size_t)(r0 + lrow) * C_EMB + p * 32 + lcol,
                           &As[p * 64 * 32 + r0 * 32]);
            }
#pragma unroll
            for (int i = 0; i < 6; ++i) {   // B: 384 rows
                int r0 = (i * 4 + wave) * 16;
                load16_lds(Bb + (size_t)(r0 + lrow) * C_EMB + p * 32 + lcol,
                           &Bs[p * 384 * 32 + r0 * 32]);
            }
        }
        __syncthreads();

        bf16_8 af[2][2], bf[12][2];
#pragma unroll
        for (int p = 0; p < 2; ++p) {
#pragma unroll
            for (int i = 0; i < 2; ++i)
                af[i][p] = *reinterpret_cast<const bf16_8*>(
                    &As[p * 64 * 32 + (wr * 32 + i * 16 + l16) * 32 + quad * 8]);
#pragma unroll
            for (int j = 0; j < 12; ++j)
                bf[j][p] = *reinterpret_cast<const bf16_8*>(
                    &Bs[p * 384 * 32 + (wc * 192 + j * 16 + l16) * 32 + quad * 8]);
        }
#pragma unroll
        for (int i = 0; i < 2; ++i)
#pragma unroll
            for (int j = 0; j < 12; ++j) {
                acc[i][j] = __builtin_amdgcn_mfma_f32_16x16x32_bf16(af[i][0], bf[j][0], acc[i][j], 0, 0, 0);
                acc[i][j] = __builtin_amdgcn_mfma_f32_16x16x32_bf16(af[i][1], bf[j][1], acc[i][j], 0, 0, 0);
            }
        __syncthreads();
    }

    // per-thread column constants (same cols for every row this thread touches)
    float bia[12], gg[12], bb[12];
#pragma unroll
    for (int j = 0; j < 12; ++j) {
        int n = wc * 192 + j * 16 + l16;
        bia[j] = bias[n];
        gg[j] = lng[n];
        bb[j] = lnb[n];
    }

    // pass 1: v = acc + bias + resid (in-place), row sum & sumsq -> red
#pragma unroll
    for (int i = 0; i < 2; ++i)
#pragma unroll
        for (int r = 0; r < 4; ++r) {
            int rloc = wr * 32 + i * 16 + quad * 4 + r;
            int m = bm + rloc;
            float s = 0.0f, s2 = 0.0f;
#pragma unroll
            for (int j = 0; j < 12; ++j) {
                int n = wc * 192 + j * 16 + l16;
                float v = acc[i][j][r] + bia[j] + resid[(size_t)m * C_EMB + n];
                acc[i][j][r] = v;
                s += v;
                s2 += v * v;
            }
#pragma unroll
            for (int o = 8; o; o >>= 1) {
                s += __shfl_xor(s, o);
                s2 += __shfl_xor(s2, o);
            }
            if (l16 == 0) {
                red[0][wc][rloc] = s;
                red[1][wc][rloc] = s2;
            }
        }
    __syncthreads();

    // pass 2: normalize + write out (fp32) and h (bf16 LN)
#pragma unroll
    for (int i = 0; i < 2; ++i)
#pragma unroll
        for (int r = 0; r < 4; ++r) {
            int rloc = wr * 32 + i * 16 + quad * 4 + r;
            int m = bm + rloc;
            float mu  = (red[0][0][rloc] + red[0][1][rloc]) * (1.0f / C_EMB);
            float ex2 = (red[1][0][rloc] + red[1][1][rloc]) * (1.0f / C_EMB);
            float rstd = rsqrtf(ex2 - mu * mu + 1e-5f);
#pragma unroll
            for (int j = 0; j < 12; ++j) {
                int n = wc * 192 + j * 16 + l16;
                float v = acc[i][j][r];
                out[(size_t)m * C_EMB + n] = v;
                h[(size_t)m * C_EMB + n] = (__bf16)((v - mu) * rstd * gg[j] + bb[j]);
            }
        }
}

// ---------------- V transpose: Vt[b][c][s] = qkv[b][s][768+c] -------------------------
__global__ __launch_bounds__(256) void vt_kernel(const __bf16* __restrict__ qkv,
                                                 __bf16* __restrict__ Vt) {
    __shared__ __align__(16) __bf16 t[32][72];
    int b = blockIdx.z, c0 = blockIdx.x * 64, s0 = blockIdx.y * 32;
    int tid = threadIdx.x;

    int tx = tid & 7, ty = tid >> 3;
    const __bf16* src = qkv + ((size_t)b * T_SEQ + s0 + ty) * QKV_LD + 768 + c0 + tx * 8;
    *reinterpret_cast<float4*>(&t[ty][tx * 8]) = *reinterpret_cast<const float4*>(src);
    __syncthreads();

    int sx = tid & 3, cy = tid >> 2;
    __align__(16) __bf16 tmp[8];
#pragma unroll
    for (int j = 0; j < 8; ++j) tmp[j] = t[sx * 8 + j][cy];
    *reinterpret_cast<float4*>(&Vt[((size_t)b * C_EMB + c0 + cy) * T_SEQ + s0 + sx * 8]) =
        *reinterpret_cast<float4*>(tmp);
}

// ---------------- Fused QK^T + causal softmax: P = softmax(scale*Q@K^T) ---------------
// Grid (2, B): bx=0 -> q-rows [0,128), 1 k-tile; bx=1 -> q-rows [128,256), 2 k-tiles.
// nt loop statically unrolled with block-uniform guard (rule #20: acc must stay
// compile-time indexed or it spills to scratch — round-3 regression).
__global__ __launch_bounds__(256) void qks_mfma(const __bf16* __restrict__ qkv,
                                                __bf16* __restrict__ P) {
    int b = blockIdx.y;
    int bx = blockIdx.x;
    int bm = bx * 128;
    int ntiles = bx + 1;
    const __bf16* Ab0 = qkv + (size_t)b * T_SEQ * QKV_LD;
    const __bf16* Bb0 = Ab0 + 384;

    __shared__ __align__(16) __bf16 As[2 * 128 * 32];
    __shared__ __align__(16) __bf16 Bs[2 * 128 * 32];
    __shared__ float red[2][2][128];   // [max|sum][wc][local row]

    int tid = threadIdx.x;
    int wave = tid >> 6, lane = tid & 63;
    int wr = wave >> 1, wc = wave & 1;
    int quad = lane >> 4, l16 = lane & 15;
    int lrow = lane >> 2, lcol = (lane & 3) * 8;

    f32x4 acc[2][4][4] = {};

#pragma unroll
    for (int nt = 0; nt < 2; ++nt) {
        if (nt < ntiles) {                      // block-uniform guard
            int bn = nt * 128;
            for (int k0 = 0; k0 < C_EMB; k0 += BK) {
                const __bf16* Ab = Ab0 + (size_t)bm * QKV_LD + k0;
                const __bf16* Bb = Bb0 + (size_t)bn * QKV_LD + k0;
#pragma unroll
                for (int p = 0; p < 2; ++p)
#pragma unroll
                    for (int i = 0; i < 2; ++i) {
                        int r0 = (i * 4 + wave) * 16;
                        load16_lds(Ab + (size_t)(r0 + lrow) * QKV_LD + p * 32 + lcol,
                                   &As[p * 128 * 32 + r0 * 32]);
                        load16_lds(Bb + (size_t)(r0 + lrow) * QKV_LD + p * 32 + lcol,
                                   &Bs[p * 128 * 32 + r0 * 32]);
                    }
                __syncthreads();

                bf16_8 af[4][2], bf[4][2];
#pragma unroll
                for (int p = 0; p < 2; ++p)
#pragma unroll
                    for (int i = 0; i < 4; ++i) {
                        af[i][p] = *reinterpret_cast<const bf16_8*>(
                            &As[p * 128 * 32 + (wr * 64 + i * 16 + l16) * 32 + quad * 8]);
                        bf[i][p] = *reinterpret_cast<const bf16_8*>(
                            &Bs[p * 128 * 32 + (wc * 64 + i * 16 + l16) * 32 + quad * 8]);
                    }
#pragma unroll
                for (int i = 0; i < 4; ++i)
#pragma unroll
                    for (int j = 0; j < 4; ++j) {
                        acc[nt][i][j] = __builtin_amdgcn_mfma_f32_16x16x32_bf16(af[i][0], bf[j][0], acc[nt][i][j], 0, 0, 0);
                        acc[nt][i][j] = __builtin_amdgcn_mfma_f32_16x16x32_bf16(af[i][1], bf[j][1], acc[nt][i][j], 0, 0, 0);
                    }
                __syncthreads();
            }
        }
    }

    // ---- softmax epilogue (fp32 in-register) ----
    const float scale = 0.05103103630798288f;

    // 1) per-row max: local (nt,j) -> shfl over l16 -> LDS across the 2 wc-waves
#pragma unroll
    for (int i = 0; i < 4; ++i)
#pragma unroll
        for (int r = 0; r < 4; ++r) {
            int rloc = wr * 64 + i * 16 + quad * 4 + r;
            int t = bm + rloc;
            float m = -INFINITY;
#pragma unroll
            for (int nt = 0; nt < 2; ++nt)
#pragma unroll
                for (int j = 0; j < 4; ++j) {
                    int n = nt * 128 + wc * 64 + j * 16 + l16;
                    bool ok = (nt < ntiles) && (n <= t);
                    float v = acc[nt][i][j][r] * scale;
                    m = fmaxf(m, ok ? v : -INFINITY);
                }
#pragma unroll
            for (int o = 8; o; o >>= 1) m = fmaxf(m, __shfl_xor(m, o));
            if (l16 == 0) red[0][wc][rloc] = m;
        }
    __syncthreads();

    // 2) exp + per-row sum (same reduction path); p values overwrite acc
#pragma unroll
    for (int i = 0; i < 4; ++i)
#pragma unroll
        for (int r = 0; r < 4; ++r) {
            int rloc = wr * 64 + i * 16 + quad * 4 + r;
            int t = bm + rloc;
            float M = fmaxf(red[0][0][rloc], red[0][1][rloc]);
            float s = 0.0f;
#pragma unroll
            for (int nt = 0; nt < 2; ++nt)
#pragma unroll
                for (int j = 0; j < 4; ++j) {
                    int n = nt * 128 + wc * 64 + j * 16 + l16;
                    bool ok = (nt < ntiles) && (n <= t);
                    float p = ok ? __expf(acc[nt][i][j][r] * scale - M) : 0.0f;
                    acc[nt][i][j][r] = p;
                    s += p;
                }
#pragma unroll
            for (int o = 8; o; o >>= 1) s += __shfl_xor(s, o);
            if (l16 == 0) red[1][wc][rloc] = s;
        }
    __syncthreads();

    // 3) normalize + write bf16 P (only the tiles this block owns; pv never reads the rest)
    __bf16* Pb_ = P + (size_t)b * T_SEQ * T_SEQ;
#pragma unroll
    for (int i = 0; i < 4; ++i)
#pragma unroll
        for (int r = 0; r < 4; ++r) {
            int rloc = wr * 64 + i * 16 + quad * 4 + r;
            float inv = 1.0f / (red[1][0][rloc] + red[1][1][rloc]);
#pragma unroll
            for (int nt = 0; nt < 2; ++nt)
                if (nt < ntiles)
#pragma unroll
                    for (int j = 0; j < 4; ++j) {
                        int n = nt * 128 + wc * 64 + j * 16 + l16;
                        Pb_[(size_t)(bm + rloc) * T_SEQ + n] = (__bf16)(acc[nt][i][j][r] * inv);
                    }
        }
}

// ---------------- Attention pass 3: y = P @ V (MFMA, causal k-skip) -------------------
__global__ __launch_bounds__(256) void pv_mfma(const __bf16* __restrict__ P,
                                               const __bf16* __restrict__ Vt,
                                               __bf16* __restrict__ y) {
    int b = blockIdx.z;
    int bm = blockIdx.y * 128, bn = blockIdx.x * 128;
    const __bf16* Ab0 = P + (size_t)b * T_SEQ * T_SEQ;
    const __bf16* Bb0 = Vt + (size_t)b * C_EMB * T_SEQ;

    __shared__ __align__(16) __bf16 As[2 * 128 * 32];
    __shared__ __align__(16) __bf16 Bs[2 * 128 * 32];

    int tid = threadIdx.x;
    int wave = tid >> 6, lane = tid & 63;
    int wr = wave >> 1, wc = wave & 1;
    int quad = lane >> 4, l16 = lane & 15;
    int lrow = lane >> 2, lcol = (lane & 3) * 8;

    f32x4 acc[4][4] = {};

    int kmax = bm + 128;   // divisible by 64
    for (int k0 = 0; k0 < kmax; k0 += BK) {
        const __bf16* Ab = Ab0 + (size_t)bm * T_SEQ + k0;
        const __bf16* Bb = Bb0 + (size_t)bn * T_SEQ + k0;
#pragma unroll
        for (int p = 0; p < 2; ++p)
#pragma unroll
            for (int i = 0; i < 2; ++i) {
                int r0 = (i * 4 + wave) * 16;
                load16_lds(Ab + (size_t)(r0 + lrow) * T_SEQ + p * 32 + lcol,
                           &As[p * 128 * 32 + r0 * 32]);
                load16_lds(Bb + (size_t)(r0 + lrow) * T_SEQ + p * 32 + lcol,
                           &Bs[p * 128 * 32 + r0 * 32]);
            }
        __syncthreads();

        bf16_8 af[4][2], bf[4][2];
#pragma unroll
        for (int p = 0; p < 2; ++p)
#pragma unroll
            for (int i = 0; i < 4; ++i) {
                af[i][p] = *reinterpret_cast<const bf16_8*>(
                    &As[p * 128 * 32 + (wr * 64 + i * 16 + l16) * 32 + quad * 8]);
                bf[i][p] = *reinterpret_cast<const bf16_8*>(
                    &Bs[p * 128 * 32 + (wc * 64 + i * 16 + l16) * 32 + quad * 8]);
            }
#pragma unroll
        for (int i = 0; i < 4; ++i)
#pragma unroll
            for (int j = 0; j < 4; ++j) {
                acc[i][j] = __builtin_amdgcn_mfma_f32_16x16x32_bf16(af[i][0], bf[j][0], acc[i][j], 0, 0, 0);
                acc[i][j] = __builtin_amdgcn_mfma_f32_16x16x32_bf16(af[i][1], bf[j][1], acc[i][j], 0, 0, 0);
            }
        __syncthreads();
    }

#pragma unroll
    for (int i = 0; i < 4; ++i) {
#pragma unroll
        for (int r = 0; r < 4; ++r) {
            int m = bm + wr * 64 + i * 16 + quad * 4 + r;
#pragma unroll
            for (int j = 0; j < 4; ++j) {
                int n = bn + wc * 64 + j * 16 + l16;
                y[((size_t)b * T_SEQ + m) * C_EMB + n] = (__bf16)acc[i][j][r];
            }
        }
    }
}

extern "C" void kernel_launch(void* const* d_in, const int* in_sizes, int n_in,
                              void* d_out, int out_size, void* d_ws, size_t ws_size,
                              hipStream_t stream) {
    const float* x      = (const float*)d_in[0];
    const float* W_attn = (const float*)d_in[1];
    const float* b_attn = (const float*)d_in[2];
    const float* W_proj = (const float*)d_in[3];
    const float* b_proj = (const float*)d_in[4];
    const float* ln1_g  = (const float*)d_in[5];
    const float* ln1_b  = (const float*)d_in[6];
    const float* ln2_g  = (const float*)d_in[7];
    const float* ln2_b  = (const float*)d_in[8];
    const float* W1     = (const float*)d_in[9];
    const float* b1     = (const float*)d_in[10];
    const float* W2     = (const float*)d_in[11];
    const float* b2     = (const float*)d_in[12];
    float* out = (float*)d_out;

    // ---- workspace (205 MB; ws >= 251.6 MB proven) ----
    __bf16* Wattn_t = (__bf16*)d_ws;                            // [1152,384]
    __bf16* Wproj_t = Wattn_t + (size_t)1152 * 384;             // [384,384]
    __bf16* W1_t    = Wproj_t + (size_t)384 * 384;              // [1536,384]
    __bf16* W2_t    = W1_t + (size_t)1536 * 384;                // [384,1536]
    __bf16* h       = W2_t + (size_t)384 * 1536;                // [M,384] bf16
    __bf16* yb      = h + (size_t)M_ROWS * 384;                 // [M,384] bf16
    __bf16* qkv     = yb + (size_t)M_ROWS * 384;                // [M,1152] bf16
    float*  S       = (float*)(qkv + (size_t)M_ROWS * QKV_LD);  // [B,T,T] fp32 (unused, layout kept)
    __bf16* Pb      = (__bf16*)(S + (size_t)B_BATCH * T_SEQ * T_SEQ);  // [B,T,T] bf16
    __bf16* Vt      = Pb + (size_t)B_BATCH * T_SEQ * T_SEQ;     // [B,384,T] bf16
    __bf16* ff      = qkv;                                      // [M,1536] bf16 alias

    // 0. weights → bf16 [N,K], one dispatch (432+144+576+576 = 1728 tiles)
    cast_all_kernel<<<1728, 256, 0, stream>>>(W_attn, W_proj, W1, W2,
                                              Wattn_t, Wproj_t, W1_t, W2_t);

    // 1. h = bf16(LN1(x))
    ln_kernel<<<M_ROWS, 384, 0, stream>>>(x, ln1_g, ln1_b, h);
    // 2. qkv = bf16(h @ W_attn + b_attn)   (pipe2: 2 blocks/CU + XCD swizzle)
    gemm_pipe2<384, 1152, 6, false, false><<<dim3(6, M_ROWS / 128), 256, 0, stream>>>(
        h, Wattn_t, b_attn, qkv);
    // 3. attention (bf16 MFMA core; QK^T + causal softmax fused)
    vt_kernel<<<dim3(C_EMB / 64, T_SEQ / 32, B_BATCH), 256, 0, stream>>>(qkv, Vt);
    qks_mfma<<<dim3(2, B_BATCH), 256, 0, stream>>>(qkv, Pb);
    pv_mfma<<<dim3(C_EMB / 128, T_SEQ / 128, B_BATCH), 256, 0, stream>>>(Pb, Vt, yb);
    // 4+5. out = x + yb @ W_proj + b_proj ; h = bf16(LN2(out))   (fused)
    proj_ln_kernel<<<M_ROWS / 64, 256, 0, stream>>>(yb, Wproj_t, b_proj, x,
                                                    ln2_g, ln2_b, out, h);
    // 6. ff = bf16(relu(h2 @ W1 + b1))   (pipe2 + XCD swizzle)
    gemm_pipe2<384, 1536, 8, true, false><<<dim3(8, M_ROWS / 128), 256, 0, stream>>>(
        h, W1_t, b1, ff);
    // 7. out += ff @ W2 + b2   (pipe2 + XCD swizzle)
    gemm_pipe2<1536, 384, 2, false, true><<<dim3(2, M_ROWS / 128), 256, 0, stream>>>(
        ff, W2_t, b2, out);
}